// Round 8
// baseline (375.929 us; speedup 1.0000x reference)
//
#include <hip/hip_runtime.h>
#include <hip/hip_bf16.h>

// Problem constants
#define BB 2
#define SS 2048
#define DD 2048
#define HH 16
#define DKK 128
#define MM (BB*SS)   // 4096 token rows

typedef unsigned short u16;
typedef short bf16x8 __attribute__((ext_vector_type(8)));
typedef unsigned short u16x8 __attribute__((ext_vector_type(8)));
typedef float f32x4 __attribute__((ext_vector_type(4)));

static __device__ __forceinline__ f32x4 mfma_bf16(bf16x8 a, bf16x8 b, f32x4 c) {
  return __builtin_amdgcn_mfma_f32_16x16x32_bf16(a, b, c, 0, 0, 0);
}

// fp32 -> bf16 RNE (bit-twiddle)
static __device__ __forceinline__ u16 f2b(float f) {
  unsigned int u = __float_as_uint(f);
  u = (u + 0x7FFFu + ((u >> 16) & 1u)) >> 16;
  return (u16)u;
}

// packed fp32x2 -> bf16x2 RNE via v_cvt_pk_bf16_f32 (1 VALU op)
static __device__ __forceinline__ unsigned int cvt2(float lo, float hi) {
  unsigned int r;
  asm("v_cvt_pk_bf16_f32 %0, %1, %2" : "=v"(r) : "v"(lo), "v"(hi));
  return r;
}
static __device__ __forceinline__ u16 f2bq(float f) { return (u16)cvt2(f, f); }

// async global->LDS, 16B/lane. LDS dest = wave-uniform base + lane*16.
static __device__ __forceinline__ void gl16(const u16* g, u16* l) {
  __builtin_amdgcn_global_load_lds(
      (const __attribute__((address_space(1))) unsigned int*)(const void*)g,
      (__attribute__((address_space(3))) unsigned int*)(void*)l, 16, 0, 0);
}

// fp32->bf16 prepass: WEIGHTS ONLY (wq,wk,wv,wo) + RoPE cos/sin table.
// q/k/v conversion is fused into the QKV GEMM (A-side reg-stage convert),
// removing 96MB read + 48MB write from this HBM-bound pass.
struct F2BArgs { const float* src[4]; u16* dst[4]; const float* fa; float* cs; };
__global__ __launch_bounds__(256) void k_f2bf_w(F2BArgs a) {
  int bid = blockIdx.x;
  if (bid >= 8192) {
    // cos/sin table: cs[2*t] = cos(fa[t]), cs[2*t+1] = sin(fa[t]); 8 t/thread.
    const int t0 = ((bid - 8192) * 256 + threadIdx.x) * 8;
    float4 a0 = *reinterpret_cast<const float4*>(a.fa + t0);
    float4 a1 = *reinterpret_cast<const float4*>(a.fa + t0 + 4);
    float4 o0, o1, o2, o3;
    o0.x = cosf(a0.x); o0.y = sinf(a0.x); o0.z = cosf(a0.y); o0.w = sinf(a0.y);
    o1.x = cosf(a0.z); o1.y = sinf(a0.z); o1.z = cosf(a0.w); o1.w = sinf(a0.w);
    o2.x = cosf(a1.x); o2.y = sinf(a1.x); o2.z = cosf(a1.y); o2.w = sinf(a1.y);
    o3.x = cosf(a1.z); o3.y = sinf(a1.z); o3.z = cosf(a1.w); o3.w = sinf(a1.w);
    float* out = a.cs + 2 * t0;
    *reinterpret_cast<float4*>(out)      = o0;
    *reinterpret_cast<float4*>(out + 4)  = o1;
    *reinterpret_cast<float4*>(out + 8)  = o2;
    *reinterpret_cast<float4*>(out + 12) = o3;
    return;
  }
  const int buf = bid >> 11;          // 4 x 2048 blocks
  const int local = bid & 2047;
  const int i = (local * 256 + threadIdx.x) * 8;
  const float* in = a.src[buf];
  float4 v0 = *reinterpret_cast<const float4*>(in + i);
  float4 v1 = *reinterpret_cast<const float4*>(in + i + 4);
  u16x8 o;
  o[0]=f2b(v0.x); o[1]=f2b(v0.y); o[2]=f2b(v0.z); o[3]=f2b(v0.w);
  o[4]=f2b(v1.x); o[5]=f2b(v1.y); o[6]=f2b(v1.z); o[7]=f2b(v1.w);
  *reinterpret_cast<u16x8*>(a.dst[buf] + i) = o;
}

struct GemmJob { const void* A; const u16* W; const float* bias; void* out; int mode; };
struct GemmArgs { GemmJob job[3]; };

// ============================================================================
// k_gemmT<AF32>: 128x128 tile, BK=64, LDS double-buffer, issue-next-first.
// AF32=0: A is bf16, staged via gl16 (pre-swizzled source column).
// AF32=1: A is fp32, staged via reg-load -> v_cvt_pk_bf16_f32 -> swizzled
//         ds_write_b128 (T14 split: loads issued before compute, write after;
//         the write targets sA[(t+1)&1], whose last readers were separated by
//         the barrier at the end of step t-1 -> no extra barrier needed).
// B is always bf16 weights via gl16. T2 XOR swizzle both paths:
// LDS[row][c] = global[row][c ^ (row&7)*8]; fragment read XOR rx=(lr&7)*8.
// LDS 64 KiB -> 2 blocks/CU. mode: 0=bf16out,1=+RoPE,3=+RoPE+scale,2=fp32out.
// ============================================================================
template <int AF32>
__global__ __launch_bounds__(256, 2) void k_gemmT(GemmArgs ga, const float* __restrict__ cs) {
  const GemmJob J = ga.job[blockIdx.z];
  const u16* __restrict__ W = J.W;
  const int mode = J.mode;
  const int K = DD, N = DD;
  const int KT = K / 64;   // 32

  __shared__ __align__(16) u16 sA[2][128 * 64];   // 32 KiB
  __shared__ __align__(16) u16 sB[2][128 * 64];   // 32 KiB
  const int tid = threadIdx.x;
  const int l  = tid & 63;
  const int w  = tid >> 6;
  const int wr = w >> 1, wc = w & 1;
  const int bm = blockIdx.x * 128, bn = blockIdx.y * 128;
  const int lr = l & 15;
  const int lg = l >> 4;

  f32x4 acc[4][4];
#pragma unroll
  for (int mi = 0; mi < 4; mi++)
#pragma unroll
    for (int ni = 0; ni < 4; ni++)
#pragma unroll
      for (int j = 0; j < 4; j++) acc[mi][ni][j] = 0.0f;

  // common staging geometry: lane l -> row base + i*8 + (l>>3)
  const int srcx = ((l & 7) * 8) ^ ((l >> 3) * 8);   // pre-swizzled src col (gl16)
  const int cx   = srcx;                              // ds_write col (same XOR)
  const u16* gAl16 = (const u16*)J.A + (size_t)(bm + w*32 + (l >> 3)) * K + srcx;
  const float* gA32 = (const float*)J.A + (size_t)(bm + w*32 + (l >> 3)) * K + (l & 7) * 8;
  const u16* gBl = W + (size_t)(bn + w*32 + (l >> 3)) * K + srcx;
  const int rowbase = (w*32 + (l >> 3)) * 64;

  const int rx = (lr & 7) * 8;

  float4 ar[4][2];   // A fp32 in-flight regs (AF32 path)

  auto loadA32 = [&](int kt) {
    const float* g = gA32 + kt * 64;
#pragma unroll
    for (int i = 0; i < 4; i++) {
      ar[i][0] = *reinterpret_cast<const float4*>(g + (size_t)i*8*K);
      ar[i][1] = *reinterpret_cast<const float4*>(g + (size_t)i*8*K + 4);
    }
  };
  auto writeA32 = [&](int kt) {
    u16* dA = &sA[kt & 1][0];
#pragma unroll
    for (int i = 0; i < 4; i++) {
      uint4 o;
      o.x = cvt2(ar[i][0].x, ar[i][0].y);
      o.y = cvt2(ar[i][0].z, ar[i][0].w);
      o.z = cvt2(ar[i][1].x, ar[i][1].y);
      o.w = cvt2(ar[i][1].z, ar[i][1].w);
      *reinterpret_cast<uint4*>(dA + rowbase + i*8*64 + cx) = o;
    }
  };
  auto stageA16 = [&](int kt) {
    u16* dA = &sA[kt & 1][(w * 32) * 64];
    const int k0 = kt * 64;
#pragma unroll
    for (int i = 0; i < 4; i++) gl16(gAl16 + (size_t)i*8*K + k0, dA + i * 512);
  };
  auto stageB = [&](int kt) {
    u16* dB = &sB[kt & 1][(w * 32) * 64];
    const int k0 = kt * 64;
#pragma unroll
    for (int i = 0; i < 4; i++) gl16(gBl + (size_t)i*8*K + k0, dB + i * 512);
  };

  // prologue: tile 0
  stageB(0);
  if (AF32) { loadA32(0); writeA32(0); }
  else      { stageA16(0); }
  __syncthreads();   // drains gl16s + ds_writes visible

#pragma unroll 1
  for (int t = 0; t < KT; t++) {
    if (t + 1 < KT) {
      stageB(t + 1);                     // gl16, drained at end-of-step barrier
      if (AF32) loadA32(t + 1);          // issue early, consume after compute
      else      stageA16(t + 1);
    }
    const u16* a_ = sA[t & 1];
    const u16* b_ = sB[t & 1];
#pragma unroll
    for (int kk = 0; kk < 2; kk++) {
      bf16x8 af[4], bfv[4];
#pragma unroll
      for (int i = 0; i < 4; i++)
        af[i]  = *reinterpret_cast<const bf16x8*>(
            a_ + (wr*64 + i*16 + lr) * 64 + ((kk*32 + lg*8) ^ rx));
#pragma unroll
      for (int i = 0; i < 4; i++)
        bfv[i] = *reinterpret_cast<const bf16x8*>(
            b_ + (wc*64 + i*16 + lr) * 64 + ((kk*32 + lg*8) ^ rx));
#pragma unroll
      for (int mi = 0; mi < 4; mi++)
#pragma unroll
        for (int ni = 0; ni < 4; ni++)
          acc[mi][ni] = mfma_bf16(af[mi], bfv[ni], acc[mi][ni]);
    }
    if (AF32 && t + 1 < KT) writeA32(t + 1);   // vmcnt wait covered by compute
    __syncthreads();
  }

  // Epilogue. D-layout: col = lane&15, row = (lane>>4)*4 + reg.
#pragma unroll
  for (int mi = 0; mi < 4; mi++) {
#pragma unroll
    for (int ni = 0; ni < 4; ni++) {
      const int col = bn + wc*64 + ni*16 + lr;
      const float bv = J.bias[col];
#pragma unroll
      for (int r = 0; r < 4; r++) {
        const int row = bm + wr*64 + mi*16 + lg*4 + r;
        float v = acc[mi][ni][r] + bv;
        if (mode & 1) {
          const int s  = row & (SS - 1);
          const int dk = col & (DKK - 1);
          const int p  = dk >> 1;
          const float2 csv = *reinterpret_cast<const float2*>(cs + (size_t)(s*64 + p)*2);
          const float other = __shfl_xor(v, 1);
          const float sgn = (dk & 1) ? csv.y : -csv.y;
          v = v * csv.x + other * sgn;
          if (mode == 3) v *= 0.12751744f;   // (1/sqrt(128)) * log2(e)
        }
        if (mode == 2) {
          reinterpret_cast<float*>(J.out)[(size_t)row * N + col] = v;
        } else {
          reinterpret_cast<u16*>(J.out)[(size_t)row * N + col] = f2b(v);
        }
      }
    }
  }
}

// ============================================================================
// Flash attention, causal, exp2 domain. KVBLK=64, LDS 66 KB -> 2 blocks/CU.
// One 128-row q-tile per block, 4 waves x 32 rows. Heavy/light blocks paired
// as (bid, bid+256). kv counts 64-key tiles; mask applies when kv >= 2qt.
// ============================================================================
__global__ __launch_bounds__(256, 2) void k_attn(const u16* __restrict__ Qp,
                                                 const u16* __restrict__ Kp,
                                                 const u16* __restrict__ Vp,
                                                 u16* __restrict__ Op) {
  const int bid = blockIdx.x;
  int bh, qt;
  if (bid < 256) { bh = bid & 31; qt = 15 - (bid >> 5); }   // heavy first
  else { int b2 = bid - 256; bh = b2 & 31; qt = b2 >> 5; }  // light partner
  const int h  = bh & 15;
  const int b  = bh >> 4;
  const int tid = threadIdx.x;
  const int l  = tid & 63, w = tid >> 6;
  const int lr = l & 15, lg = l >> 4;

  __shared__ __align__(16) u16 Klds[2 * 64 * 128];  // 32 KB (dbuf)
  __shared__ __align__(16) u16 VT[128 * 64];        // 16 KB
  __shared__ __align__(16) u16 PL[4][32][72];       // 18 KB

  // K staging: wave w stages rows [w*16, w*16+16), 4 gl16 of 4 rows each.
  int koff[4];
#pragma unroll
  for (int i = 0; i < 4; i++) {
    const int row = w*16 + i*4 + (l >> 4);
    koff[i] = row * DD + (((l & 15) * 8) ^ ((row & 7) * 8));
  }
  const u16* kbase = Kp + (size_t)b * SS * DD + h * DKK;

  // V staging: thread -> keys k0v..k0v+7 (8 rows) x d-range d0..d0+3 (uint2).
  const int k0v = (tid >> 5) * 8;   // 0,8,...,56
  const int d0  = (tid & 31) * 4;   // 0,4,...,124
  const u16* vbase = Vp + (size_t)b * SS * DD + h * DKK + (size_t)k0v * DD + d0;

  uint2 vr[8];

  auto stageK = [&](int nk, int bufq) {
    const u16* kb = kbase + (size_t)nk * (64 * DD);
    u16* dst = Klds + bufq * 8192 + (w * 16) * 128;
#pragma unroll
    for (int i = 0; i < 4; i++) gl16(kb + koff[i], dst + i * 512);
  };
  auto prefV = [&](int nk) {
    const u16* vb = vbase + (size_t)nk * (64 * DD);
#pragma unroll
    for (int c = 0; c < 8; c++) vr[c] = *reinterpret_cast<const uint2*>(vb + c * DD);
  };

  int cur = 0;
  stageK(0, 0);
  prefV(0);

  // Hoist Q fragments: 2 row-tiles x 4 k-slices
  bf16x8 qf[2][4];
#pragma unroll
  for (int mt = 0; mt < 2; mt++) {
    const size_t qrow = (size_t)(b*SS + qt*128 + w*32 + mt*16 + lr) * DD + h*DKK;
#pragma unroll
    for (int kk = 0; kk < 4; kk++)
      qf[mt][kk] = *reinterpret_cast<const bf16x8*>(Qp + qrow + kk*32 + lg*8);
  }

  float m[2][4], lsum[2][4];
  f32x4 oacc[2][8];
#pragma unroll
  for (int mt = 0; mt < 2; mt++)
#pragma unroll
    for (int r = 0; r < 4; r++) { m[mt][r] = -INFINITY; lsum[mt][r] = 0.0f; }
#pragma unroll
  for (int mt = 0; mt < 2; mt++)
#pragma unroll
    for (int dt = 0; dt < 8; dt++)
#pragma unroll
      for (int jj = 0; jj < 4; jj++) oacc[mt][dt][jj] = 0.0f;

  const int kvmax = 2 * qt + 1;
#pragma unroll 1
  for (int kv = 0; kv <= kvmax; kv++) {
    __syncthreads();   // prev iter LDS reads done; K[cur] gl16 + vr loads drained
    // write prefetched V -> swizzled VT: VT[row=d][col=key ^ g(row)]
#pragma unroll
    for (int dj = 0; dj < 4; dj++) {
      const int row = d0 + dj;
      const int col = k0v ^ (((row ^ (row >> 3)) & 7) * 8);
      u16x8 pk;
#pragma unroll
      for (int j = 0; j < 8; j++) pk[j] = reinterpret_cast<const u16*>(&vr[j])[dj];
      *reinterpret_cast<u16x8*>(VT + row * 64 + col) = pk;
    }
    __syncthreads();   // VT ready; K[cur] visible to all waves

    const bool hasnext = (kv < kvmax);
    if (hasnext) {
      prefV(kv + 1);               // global->reg, hides under compute
      stageK(kv + 1, cur ^ 1);     // gl16, drained at next top barrier
    }

    // ---- S = Q K^T (32 q-rows x 64 keys per wave) ----
    f32x4 sa[2][4];
#pragma unroll
    for (int mt = 0; mt < 2; mt++)
#pragma unroll
      for (int kt = 0; kt < 4; kt++)
#pragma unroll
        for (int jj = 0; jj < 4; jj++) sa[mt][kt][jj] = 0.0f;
    const u16* kl = Klds + cur * 8192;
    __builtin_amdgcn_s_setprio(1);
#pragma unroll
    for (int kk = 0; kk < 4; kk++) {
#pragma unroll
      for (int kt = 0; kt < 4; kt++) {
        const int row = kt*16 + lr;
        const bf16x8 kf = *reinterpret_cast<const bf16x8*>(
            kl + row * 128 + ((kk*32 + lg*8) ^ ((row & 7) * 8)));
#pragma unroll
        for (int mt = 0; mt < 2; mt++)
          sa[mt][kt] = mfma_bf16(qf[mt][kk], kf, sa[mt][kt]);
      }
    }
    __builtin_amdgcn_s_setprio(0);

    // causal mask: the two kv tiles overlapping the diagonal
    if (kv >= 2 * qt) {
#pragma unroll
      for (int kt = 0; kt < 4; kt++) {
        const int key = kv*64 + kt*16 + lr;
#pragma unroll
        for (int mt = 0; mt < 2; mt++)
#pragma unroll
          for (int r = 0; r < 4; r++) {
            const int qv = qt*128 + w*32 + mt*16 + lg*4 + r;
            if (key > qv) sa[mt][kt][r] = -1e9f;
          }
      }
    }

    // defer-max (THR=8): lane-local check, rescale rarely
    float pm[2][4];
#pragma unroll
    for (int mt = 0; mt < 2; mt++)
#pragma unroll
      for (int r = 0; r < 4; r++)
        pm[mt][r] = fmaxf(fmaxf(sa[mt][0][r], sa[mt][1][r]),
                          fmaxf(sa[mt][2][r], sa[mt][3][r]));
    bool ok = true;
#pragma unroll
    for (int mt = 0; mt < 2; mt++)
#pragma unroll
      for (int r = 0; r < 4; r++) ok = ok && (pm[mt][r] <= m[mt][r] + 8.0f);
    if (!__all(ok)) {
#pragma unroll
      for (int mt = 0; mt < 2; mt++)
#pragma unroll
        for (int r = 0; r < 4; r++) {
          float t = pm[mt][r];
#pragma unroll
          for (int d = 1; d < 16; d <<= 1) t = fmaxf(t, __shfl_xor(t, d));
          const float mnew = fmaxf(m[mt][r], t);
          const float corr = exp2f(m[mt][r] - mnew);
          lsum[mt][r] *= corr;
#pragma unroll
          for (int dt = 0; dt < 8; dt++) oacc[mt][dt][r] *= corr;
          m[mt][r] = mnew;
        }
    }

    // exp2 + lane-partial sums + P -> per-wave LDS
#pragma unroll
    for (int mt = 0; mt < 2; mt++)
#pragma unroll
      for (int r = 0; r < 4; r++) {
        float rs = 0.0f;
#pragma unroll
        for (int kt = 0; kt < 4; kt++) {
          const float e = exp2f(sa[mt][kt][r] - m[mt][r]);
          rs += e;
          PL[w][mt*16 + lg*4 + r][kt*16 + lr] = f2bq(e);
        }
        lsum[mt][r] += rs;
      }

    // ---- O += P V ----
    __builtin_amdgcn_s_setprio(1);
#pragma unroll
    for (int kk2 = 0; kk2 < 2; kk2++) {
      bf16x8 pa[2];
#pragma unroll
      for (int mt = 0; mt < 2; mt++)
        pa[mt] = *reinterpret_cast<const bf16x8*>(&PL[w][mt*16 + lr][kk2*32 + lg*8]);
#pragma unroll
      for (int dt = 0; dt < 8; dt++) {
        const int row = dt*16 + lr;
        const bf16x8 vb = *reinterpret_cast<const bf16x8*>(
            VT + row * 64 + ((kk2*32 + lg*8) ^ (((row ^ (row >> 3)) & 7) * 8)));
#pragma unroll
        for (int mt = 0; mt < 2; mt++)
          oacc[mt][dt] = mfma_bf16(pa[mt], vb, oacc[mt][dt]);
      }
    }
    __builtin_amdgcn_s_setprio(0);

    if (hasnext) cur ^= 1;
  }

  // epilogue: reduce lane-partial lsum across 16 lanes, normalize, store
  float inv[2][4];
#pragma unroll
  for (int mt = 0; mt < 2; mt++)
#pragma unroll
    for (int r = 0; r < 4; r++) {
      float t = lsum[mt][r];
#pragma unroll
      for (int d = 1; d < 16; d <<= 1) t += __shfl_xor(t, d);
      inv[mt][r] = 1.0f / t;
    }
#pragma unroll
  for (int mt = 0; mt < 2; mt++)
#pragma unroll
    for (int dt = 0; dt < 8; dt++)
#pragma unroll
      for (int r = 0; r < 4; r++) {
        const size_t row = (size_t)(b*SS + qt*128 + w*32 + mt*16 + lg*4 + r);
        Op[row * DD + h*DKK + dt*16 + lr] = f2bq(oacc[mt][dt][r] * inv[mt][r]);
      }
}

extern "C" void kernel_launch(void* const* d_in, const int* in_sizes, int n_in,
                              void* d_out, int out_size, void* d_ws, size_t ws_size,
                              hipStream_t stream) {
  const float* q  = (const float*)d_in[0];
  const float* k  = (const float*)d_in[1];
  const float* v  = (const float*)d_in[2];
  const float* fa = (const float*)d_in[4];
  const float* wq = (const float*)d_in[5];
  const float* bq = (const float*)d_in[6];
  const float* wk = (const float*)d_in[7];
  const float* bk = (const float*)d_in[8];
  const float* wv = (const float*)d_in[9];
  const float* bv = (const float*)d_in[10];
  const float* wo = (const float*)d_in[11];
  const float* bo = (const float*)d_in[12];

  float* cs = (float*)d_ws;
  u16* bf = (u16*)((char*)d_ws + (size_t)262144 * sizeof(float));
  const size_t NX = (size_t)MM * DD;
  const size_t NW = (size_t)DD * DD;
  u16* q_bf  = bf;           // slots kept for layout stability (q/k/v unused)
  u16* k_bf  = q_bf + NX;
  u16* v_bf  = k_bf + NX;
  u16* wq_bf = v_bf + NX;
  u16* wk_bf = wq_bf + NW;
  u16* wv_bf = wk_bf + NW;
  u16* wo_bf = wv_bf + NW;
  u16* Qp    = wo_bf + NW;
  u16* Kp    = Qp + NX;
  u16* Vp    = Kp + NX;
  u16* Ao    = Vp + NX;

  F2BArgs fw;
  fw.src[0] = wq; fw.dst[0] = wq_bf;
  fw.src[1] = wk; fw.dst[1] = wk_bf;
  fw.src[2] = wv; fw.dst[2] = wv_bf;
  fw.src[3] = wo; fw.dst[3] = wo_bf;
  fw.fa = fa;     fw.cs = cs;
  // 4x2048 weight-conversion blocks + 64 cos/sin blocks
  k_f2bf_w<<<dim3(8256), 256, 0, stream>>>(fw);

  // fused QKV projections: fp32-A convert-in-kernel, grid 32x16x3 = 1536
  GemmArgs gq;
  gq.job[0] = GemmJob{ (const void*)q, wq_bf, bq, (void*)Qp, 3 };
  gq.job[1] = GemmJob{ (const void*)k, wk_bf, bk, (void*)Kp, 1 };
  gq.job[2] = GemmJob{ (const void*)v, wv_bf, bv, (void*)Vp, 0 };
  k_gemmT<1><<<dim3(MM/128, DD/128, 3), 256, 0, stream>>>(gq, cs);

  k_attn<<<dim3(512), 256, 0, stream>>>(Qp, Kp, Vp, Ao);

  // output projection: bf16-A gl16 path, 512 blocks = 2/CU, one round
  GemmArgs go;
  go.job[0] = GemmJob{ (const void*)Ao, wo_bf, bo, d_out, 2 };
  go.job[1] = go.job[0];
  go.job[2] = go.job[0];
  k_gemmT<0><<<dim3(MM/128, DD/128, 1), 256, 0, stream>>>(go, cs);
}

// Round 9
// 323.579 us; speedup vs baseline: 1.1618x; 1.1618x over previous
//
#include <hip/hip_runtime.h>
#include <hip/hip_bf16.h>

// Problem constants
#define BB 2
#define SS 2048
#define DD 2048
#define HH 16
#define DKK 128
#define MM (BB*SS)   // 4096 token rows

typedef unsigned short u16;
typedef short bf16x8 __attribute__((ext_vector_type(8)));
typedef unsigned short u16x8 __attribute__((ext_vector_type(8)));
typedef float f32x4 __attribute__((ext_vector_type(4)));

static __device__ __forceinline__ f32x4 mfma_bf16(bf16x8 a, bf16x8 b, f32x4 c) {
  return __builtin_amdgcn_mfma_f32_16x16x32_bf16(a, b, c, 0, 0, 0);
}

// fp32 -> bf16 RNE (bit-twiddle, prepass)
static __device__ __forceinline__ u16 f2b(float f) {
  unsigned int u = __float_as_uint(f);
  u = (u + 0x7FFFu + ((u >> 16) & 1u)) >> 16;
  return (u16)u;
}

// fp32 -> bf16 RNE via v_cvt_pk_bf16_f32 (1 VALU op; hot path)
static __device__ __forceinline__ u16 f2bq(float f) {
  unsigned int r;
  asm("v_cvt_pk_bf16_f32 %0, %1, %2" : "=v"(r) : "v"(f), "v"(f));
  return (u16)r;
}

// async global->LDS, 16B/lane. LDS dest = wave-uniform base + lane*16.
static __device__ __forceinline__ void gl16(const u16* g, u16* l) {
  __builtin_amdgcn_global_load_lds(
      (const __attribute__((address_space(1))) unsigned int*)(const void*)g,
      (__attribute__((address_space(3))) unsigned int*)(void*)l, 16, 0, 0);
}

// Fused fp32->bf16 for all 7 tensors (8 elems/thread, 16B stores) PLUS the
// RoPE cos/sin table (last 64 blocks) — one launch instead of two.
struct F2BArgs { const float* src[7]; u16* dst[7]; const float* fa; float* cs; };
__global__ __launch_bounds__(256) void k_f2bf_all(F2BArgs a) {
  int bid = blockIdx.x;
  if (bid >= 20480) {
    const int t0 = ((bid - 20480) * 256 + threadIdx.x) * 8;
    float4 a0 = *reinterpret_cast<const float4*>(a.fa + t0);
    float4 a1 = *reinterpret_cast<const float4*>(a.fa + t0 + 4);
    float4 o0, o1, o2, o3;
    o0.x = cosf(a0.x); o0.y = sinf(a0.x); o0.z = cosf(a0.y); o0.w = sinf(a0.y);
    o1.x = cosf(a0.z); o1.y = sinf(a0.z); o1.z = cosf(a0.w); o1.w = sinf(a0.w);
    o2.x = cosf(a1.x); o2.y = sinf(a1.x); o2.z = cosf(a1.y); o2.w = sinf(a1.y);
    o3.x = cosf(a1.z); o3.y = sinf(a1.z); o3.z = cosf(a1.w); o3.w = sinf(a1.w);
    float* out = a.cs + 2 * t0;
    *reinterpret_cast<float4*>(out)      = o0;
    *reinterpret_cast<float4*>(out + 4)  = o1;
    *reinterpret_cast<float4*>(out + 8)  = o2;
    *reinterpret_cast<float4*>(out + 12) = o3;
    return;
  }
  int buf, local;
  if (bid < 12288) { buf = bid >> 12; local = bid & 4095; }
  else { int t = bid - 12288; buf = 3 + (t >> 11); local = t & 2047; }
  const int i = (local * 256 + threadIdx.x) * 8;
  const float* in = a.src[buf];
  float4 v0 = *reinterpret_cast<const float4*>(in + i);
  float4 v1 = *reinterpret_cast<const float4*>(in + i + 4);
  u16x8 o;
  o[0]=f2b(v0.x); o[1]=f2b(v0.y); o[2]=f2b(v0.z); o[3]=f2b(v0.w);
  o[4]=f2b(v1.x); o[5]=f2b(v1.y); o[6]=f2b(v1.z); o[7]=f2b(v1.w);
  *reinterpret_cast<u16x8*>(a.dst[buf] + i) = o;
}

struct GemmJob { const u16* A; const u16* W; const float* bias; void* out; int mode; };
struct GemmArgs { GemmJob job[3]; };

// ============================================================================
// k_gemm3: 128x128 tile, BK=64, LDS dbuf, issue-next-first (r7 structure) +
// ZERO-VALU hot-loop addressing: K-loop unrolled x2 with LITERAL buffer
// indices so every ds_read is one shared address-VGPR + offset: immediate
// (BUF*16384 + i*2048 bytes fold into the instruction); XOR column terms
// (c0/c1) and row bases hoisted. Theory: rounds 0-8 show 29% MfmaUtil
// invariant to schedule/occupancy/tile while VALUBusy=22-25% at 2 waves/SIMD
// -> ~50 addr-VALU per wave per K-step serialized between barrier and
// ds_read; removing them shortens the critical path.
// LDS 64 KiB -> 2 blocks/CU. mode: 0=bf16out,1=+RoPE,3=+RoPE+scale,2=fp32out.
// ============================================================================
__global__ __launch_bounds__(256, 2) void k_gemm3(GemmArgs ga, const float* __restrict__ cs) {
  const GemmJob J = ga.job[blockIdx.z];
  const u16* __restrict__ A = J.A;
  const u16* __restrict__ W = J.W;
  const int mode = J.mode;
  const int K = DD, N = DD;
  const int KT = K / 64;   // 32

  __shared__ __align__(16) u16 sA[2][128 * 64];   // 32 KiB
  __shared__ __align__(16) u16 sB[2][128 * 64];   // 32 KiB
  const int tid = threadIdx.x;
  const int l  = tid & 63;
  const int w  = tid >> 6;
  const int wr = w >> 1, wc = w & 1;
  const int bm = blockIdx.x * 128, bn = blockIdx.y * 128;
  const int lr = l & 15;
  const int lg = l >> 4;

  f32x4 acc[4][4];
#pragma unroll
  for (int mi = 0; mi < 4; mi++)
#pragma unroll
    for (int ni = 0; ni < 4; ni++)
#pragma unroll
      for (int j = 0; j < 4; j++) acc[mi][ni][j] = 0.0f;

  // staging geometry (T2 swizzle via pre-swizzled source column):
  // lane l -> row w*32 + i*8 + (l>>3), src col ((l&7)*8) ^ ((l>>3)*8)
  const int srcx = ((l & 7) * 8) ^ ((l >> 3) * 8);
  const u16* gAl = A + (size_t)(bm + w*32 + (l >> 3)) * K + srcx;
  const u16* gBl = W + (size_t)(bn + w*32 + (l >> 3)) * K + srcx;
  const int ldsoff = (w * 32) * 64;

  // hoisted read-address components (loop-invariant)
  const int rx = (lr & 7) * 8;
  const int ia0 = (wr*64 + lr) * 64 + ((0  + lg*8) ^ rx);   // A, kk=0
  const int ia1 = (wr*64 + lr) * 64 + ((32 + lg*8) ^ rx);   // A, kk=1
  const int ib0 = (wc*64 + lr) * 64 + ((0  + lg*8) ^ rx);   // B, kk=0
  const int ib1 = (wc*64 + lr) * 64 + ((32 + lg*8) ^ rx);   // B, kk=1

  auto stage = [&](int gk, int nb) {
    u16* dA = &sA[nb][ldsoff];
    u16* dB = &sB[nb][ldsoff];
#pragma unroll
    for (int i = 0; i < 4; i++) gl16(gAl + (size_t)i*8*DD + gk, dA + i * 512);
#pragma unroll
    for (int i = 0; i < 4; i++) gl16(gBl + (size_t)i*8*DD + gk, dB + i * 512);
  };

// BUF is a literal 0/1 -> all ds_read addresses = shared VGPR + imm offset.
#define GEMM_COMPUTE(BUF)                                                     \
  {                                                                           \
    _Pragma("unroll")                                                         \
    for (int kk = 0; kk < 2; kk++) {                                          \
      const int ia = kk ? ia1 : ia0;                                          \
      const int ib = kk ? ib1 : ib0;                                          \
      bf16x8 af[4], bfv[4];                                                   \
      _Pragma("unroll")                                                       \
      for (int i = 0; i < 4; i++)                                             \
        af[i] = *reinterpret_cast<const bf16x8*>(&sA[BUF][ia + i*1024]);      \
      _Pragma("unroll")                                                       \
      for (int i = 0; i < 4; i++)                                             \
        bfv[i] = *reinterpret_cast<const bf16x8*>(&sB[BUF][ib + i*1024]);     \
      _Pragma("unroll")                                                       \
      for (int mi = 0; mi < 4; mi++)                                          \
        _Pragma("unroll")                                                     \
        for (int ni = 0; ni < 4; ni++)                                        \
          acc[mi][ni] = mfma_bf16(af[mi], bfv[ni], acc[mi][ni]);              \
    }                                                                         \
  }

  stage(0, 0);
  __syncthreads();   // drains tile-0 loads

#pragma unroll 1
  for (int tt = 0; tt < KT; tt += 2) {
    // body 0: compute buf0 (tile tt), stage tile tt+1 -> buf1 (tt+1<=31 always)
    stage((tt + 1) * 64, 1);
    GEMM_COMPUTE(0);
    __syncthreads();
    // body 1: compute buf1 (tile tt+1), stage tile tt+2 -> buf0
    if (tt + 2 < KT) stage((tt + 2) * 64, 0);
    GEMM_COMPUTE(1);
    __syncthreads();
  }
#undef GEMM_COMPUTE

  // Epilogue. D-layout: col = lane&15, row = (lane>>4)*4 + reg.
#pragma unroll
  for (int mi = 0; mi < 4; mi++) {
#pragma unroll
    for (int ni = 0; ni < 4; ni++) {
      const int col = bn + wc*64 + ni*16 + lr;
      const float bv = J.bias[col];
#pragma unroll
      for (int r = 0; r < 4; r++) {
        const int row = bm + wr*64 + mi*16 + lg*4 + r;
        float v = acc[mi][ni][r] + bv;
        if (mode & 1) {
          const int s  = row & (SS - 1);
          const int dk = col & (DKK - 1);
          const int p  = dk >> 1;
          const float2 csv = *reinterpret_cast<const float2*>(cs + (size_t)(s*64 + p)*2);
          const float other = __shfl_xor(v, 1);
          const float sgn = (dk & 1) ? csv.y : -csv.y;
          v = v * csv.x + other * sgn;
          if (mode == 3) v *= 0.12751744f;   // (1/sqrt(128)) * log2(e)
        }
        if (mode == 2) {
          reinterpret_cast<float*>(J.out)[(size_t)row * N + col] = v;
        } else {
          reinterpret_cast<u16*>(J.out)[(size_t)row * N + col] = f2b(v);
        }
      }
    }
  }
}

// ============================================================================
// Flash attention, causal, exp2 domain. KVBLK=64, LDS 66 KB -> 2 blocks/CU.
// One 128-row q-tile per block, 4 waves x 32 rows. Heavy/light blocks paired
// as (bid, bid+256). kv counts 64-key tiles; mask applies when kv >= 2qt.
// ============================================================================
__global__ __launch_bounds__(256, 2) void k_attn(const u16* __restrict__ Qp,
                                                 const u16* __restrict__ Kp,
                                                 const u16* __restrict__ Vp,
                                                 u16* __restrict__ Op) {
  const int bid = blockIdx.x;
  int bh, qt;
  if (bid < 256) { bh = bid & 31; qt = 15 - (bid >> 5); }   // heavy first
  else { int b2 = bid - 256; bh = b2 & 31; qt = b2 >> 5; }  // light partner
  const int h  = bh & 15;
  const int b  = bh >> 4;
  const int tid = threadIdx.x;
  const int l  = tid & 63, w = tid >> 6;
  const int lr = l & 15, lg = l >> 4;

  __shared__ __align__(16) u16 Klds[2 * 64 * 128];  // 32 KB (dbuf)
  __shared__ __align__(16) u16 VT[128 * 64];        // 16 KB
  __shared__ __align__(16) u16 PL[4][32][72];       // 18 KB

  int koff[4];
#pragma unroll
  for (int i = 0; i < 4; i++) {
    const int row = w*16 + i*4 + (l >> 4);
    koff[i] = row * DD + (((l & 15) * 8) ^ ((row & 7) * 8));
  }
  const u16* kbase = Kp + (size_t)b * SS * DD + h * DKK;

  const int k0v = (tid >> 5) * 8;   // 0,8,...,56
  const int d0  = (tid & 31) * 4;   // 0,4,...,124
  const u16* vbase = Vp + (size_t)b * SS * DD + h * DKK + (size_t)k0v * DD + d0;

  uint2 vr[8];

  auto stageK = [&](int nk, int bufq) {
    const u16* kb = kbase + (size_t)nk * (64 * DD);
    u16* dst = Klds + bufq * 8192 + (w * 16) * 128;
#pragma unroll
    for (int i = 0; i < 4; i++) gl16(kb + koff[i], dst + i * 512);
  };
  auto prefV = [&](int nk) {
    const u16* vb = vbase + (size_t)nk * (64 * DD);
#pragma unroll
    for (int c = 0; c < 8; c++) vr[c] = *reinterpret_cast<const uint2*>(vb + c * DD);
  };

  int cur = 0;
  stageK(0, 0);
  prefV(0);

  bf16x8 qf[2][4];
#pragma unroll
  for (int mt = 0; mt < 2; mt++) {
    const size_t qrow = (size_t)(b*SS + qt*128 + w*32 + mt*16 + lr) * DD + h*DKK;
#pragma unroll
    for (int kk = 0; kk < 4; kk++)
      qf[mt][kk] = *reinterpret_cast<const bf16x8*>(Qp + qrow + kk*32 + lg*8);
  }

  float m[2][4], lsum[2][4];
  f32x4 oacc[2][8];
#pragma unroll
  for (int mt = 0; mt < 2; mt++)
#pragma unroll
    for (int r = 0; r < 4; r++) { m[mt][r] = -INFINITY; lsum[mt][r] = 0.0f; }
#pragma unroll
  for (int mt = 0; mt < 2; mt++)
#pragma unroll
    for (int dt = 0; dt < 8; dt++)
#pragma unroll
      for (int jj = 0; jj < 4; jj++) oacc[mt][dt][jj] = 0.0f;

  const int kvmax = 2 * qt + 1;
#pragma unroll 1
  for (int kv = 0; kv <= kvmax; kv++) {
    __syncthreads();
#pragma unroll
    for (int dj = 0; dj < 4; dj++) {
      const int row = d0 + dj;
      const int col = k0v ^ (((row ^ (row >> 3)) & 7) * 8);
      u16x8 pk;
#pragma unroll
      for (int j = 0; j < 8; j++) pk[j] = reinterpret_cast<const u16*>(&vr[j])[dj];
      *reinterpret_cast<u16x8*>(VT + row * 64 + col) = pk;
    }
    __syncthreads();

    const bool hasnext = (kv < kvmax);
    if (hasnext) {
      prefV(kv + 1);
      stageK(kv + 1, cur ^ 1);
    }

    f32x4 sa[2][4];
#pragma unroll
    for (int mt = 0; mt < 2; mt++)
#pragma unroll
      for (int kt = 0; kt < 4; kt++)
#pragma unroll
        for (int jj = 0; jj < 4; jj++) sa[mt][kt][jj] = 0.0f;
    const u16* kl = Klds + cur * 8192;
    __builtin_amdgcn_s_setprio(1);
#pragma unroll
    for (int kk = 0; kk < 4; kk++) {
#pragma unroll
      for (int kt = 0; kt < 4; kt++) {
        const int row = kt*16 + lr;
        const bf16x8 kf = *reinterpret_cast<const bf16x8*>(
            kl + row * 128 + ((kk*32 + lg*8) ^ ((row & 7) * 8)));
#pragma unroll
        for (int mt = 0; mt < 2; mt++)
          sa[mt][kt] = mfma_bf16(qf[mt][kk], kf, sa[mt][kt]);
      }
    }
    __builtin_amdgcn_s_setprio(0);

    if (kv >= 2 * qt) {
#pragma unroll
      for (int kt = 0; kt < 4; kt++) {
        const int key = kv*64 + kt*16 + lr;
#pragma unroll
        for (int mt = 0; mt < 2; mt++)
#pragma unroll
          for (int r = 0; r < 4; r++) {
            const int qv = qt*128 + w*32 + mt*16 + lg*4 + r;
            if (key > qv) sa[mt][kt][r] = -1e9f;
          }
      }
    }

    float pm[2][4];
#pragma unroll
    for (int mt = 0; mt < 2; mt++)
#pragma unroll
      for (int r = 0; r < 4; r++)
        pm[mt][r] = fmaxf(fmaxf(sa[mt][0][r], sa[mt][1][r]),
                          fmaxf(sa[mt][2][r], sa[mt][3][r]));
    bool ok = true;
#pragma unroll
    for (int mt = 0; mt < 2; mt++)
#pragma unroll
      for (int r = 0; r < 4; r++) ok = ok && (pm[mt][r] <= m[mt][r] + 8.0f);
    if (!__all(ok)) {
#pragma unroll
      for (int mt = 0; mt < 2; mt++)
#pragma unroll
        for (int r = 0; r < 4; r++) {
          float t = pm[mt][r];
#pragma unroll
          for (int d = 1; d < 16; d <<= 1) t = fmaxf(t, __shfl_xor(t, d));
          const float mnew = fmaxf(m[mt][r], t);
          const float corr = exp2f(m[mt][r] - mnew);
          lsum[mt][r] *= corr;
#pragma unroll
          for (int dt = 0; dt < 8; dt++) oacc[mt][dt][r] *= corr;
          m[mt][r] = mnew;
        }
    }

#pragma unroll
    for (int mt = 0; mt < 2; mt++)
#pragma unroll
      for (int r = 0; r < 4; r++) {
        float rs = 0.0f;
#pragma unroll
        for (int kt = 0; kt < 4; kt++) {
          const float e = exp2f(sa[mt][kt][r] - m[mt][r]);
          rs += e;
          PL[w][mt*16 + lg*4 + r][kt*16 + lr] = f2bq(e);
        }
        lsum[mt][r] += rs;
      }

    __builtin_amdgcn_s_setprio(1);
#pragma unroll
    for (int kk2 = 0; kk2 < 2; kk2++) {
      bf16x8 pa[2];
#pragma unroll
      for (int mt = 0; mt < 2; mt++)
        pa[mt] = *reinterpret_cast<const bf16x8*>(&PL[w][mt*16 + lr][kk2*32 + lg*8]);
#pragma unroll
      for (int dt = 0; dt < 8; dt++) {
        const int row = dt*16 + lr;
        const bf16x8 vb = *reinterpret_cast<const bf16x8*>(
            VT + row * 64 + ((kk2*32 + lg*8) ^ (((row ^ (row >> 3)) & 7) * 8)));
#pragma unroll
        for (int mt = 0; mt < 2; mt++)
          oacc[mt][dt] = mfma_bf16(pa[mt], vb, oacc[mt][dt]);
      }
    }
    __builtin_amdgcn_s_setprio(0);

    if (hasnext) cur ^= 1;
  }

  float inv[2][4];
#pragma unroll
  for (int mt = 0; mt < 2; mt++)
#pragma unroll
    for (int r = 0; r < 4; r++) {
      float t = lsum[mt][r];
#pragma unroll
      for (int d = 1; d < 16; d <<= 1) t += __shfl_xor(t, d);
      inv[mt][r] = 1.0f / t;
    }
#pragma unroll
  for (int mt = 0; mt < 2; mt++)
#pragma unroll
    for (int dt = 0; dt < 8; dt++)
#pragma unroll
      for (int r = 0; r < 4; r++) {
        const size_t row = (size_t)(b*SS + qt*128 + w*32 + mt*16 + lg*4 + r);
        Op[row * DD + h*DKK + dt*16 + lr] = f2bq(oacc[mt][dt][r] * inv[mt][r]);
      }
}

extern "C" void kernel_launch(void* const* d_in, const int* in_sizes, int n_in,
                              void* d_out, int out_size, void* d_ws, size_t ws_size,
                              hipStream_t stream) {
  const float* q  = (const float*)d_in[0];
  const float* k  = (const float*)d_in[1];
  const float* v  = (const float*)d_in[2];
  const float* fa = (const float*)d_in[4];
  const float* wq = (const float*)d_in[5];
  const float* bq = (const float*)d_in[6];
  const float* wk = (const float*)d_in[7];
  const float* bk = (const float*)d_in[8];
  const float* wv = (const float*)d_in[9];
  const float* bv = (const float*)d_in[10];
  const float* wo = (const float*)d_in[11];
  const float* bo = (const float*)d_in[12];

  float* cs = (float*)d_ws;
  u16* bf = (u16*)((char*)d_ws + (size_t)262144 * sizeof(float));
  const size_t NX = (size_t)MM * DD;
  const size_t NW = (size_t)DD * DD;
  u16* q_bf  = bf;
  u16* k_bf  = q_bf + NX;
  u16* v_bf  = k_bf + NX;
  u16* wq_bf = v_bf + NX;
  u16* wk_bf = wq_bf + NW;
  u16* wv_bf = wk_bf + NW;
  u16* wo_bf = wv_bf + NW;
  u16* Qp    = wo_bf + NW;
  u16* Kp    = Qp + NX;
  u16* Vp    = Kp + NX;
  u16* Ao    = Vp + NX;

  F2BArgs fa7;
  fa7.src[0] = q;  fa7.dst[0] = q_bf;
  fa7.src[1] = k;  fa7.dst[1] = k_bf;
  fa7.src[2] = v;  fa7.dst[2] = v_bf;
  fa7.src[3] = wq; fa7.dst[3] = wq_bf;
  fa7.src[4] = wk; fa7.dst[4] = wk_bf;
  fa7.src[5] = wv; fa7.dst[5] = wv_bf;
  fa7.src[6] = wo; fa7.dst[6] = wo_bf;
  fa7.fa = fa;     fa7.cs = cs;
  // 20480 conversion blocks + 64 cos/sin-table blocks
  k_f2bf_all<<<dim3(20544), 256, 0, stream>>>(fa7);

  // fused QKV projections: dbuf 128^2 kernel, grid 32x16x3 = 1536 blocks
  GemmArgs gq;
  gq.job[0] = GemmJob{ q_bf, wq_bf, bq, (void*)Qp, 3 };
  gq.job[1] = GemmJob{ k_bf, wk_bf, bk, (void*)Kp, 1 };
  gq.job[2] = GemmJob{ v_bf, wv_bf, bv, (void*)Vp, 0 };
  k_gemm3<<<dim3(MM/128, DD/128, 3), 256, 0, stream>>>(gq, cs);

  k_attn<<<dim3(512), 256, 0, stream>>>(Qp, Kp, Vp, Ao);

  // output projection: 512 blocks = exactly 2 blocks/CU, one round
  GemmArgs go;
  go.job[0] = GemmJob{ Ao, wo_bf, bo, d_out, 2 };
  go.job[1] = go.job[0];
  go.job[2] = go.job[0];
  k_gemm3<<<dim3(MM/128, DD/128, 1), 256, 0, stream>>>(go, cs);
}

// Round 10
// 304.251 us; speedup vs baseline: 1.2356x; 1.0635x over previous
//
#include <hip/hip_runtime.h>
#include <hip/hip_bf16.h>

// Problem constants
#define BB 2
#define SS 2048
#define DD 2048
#define HH 16
#define DKK 128
#define MM (BB*SS)   // 4096 token rows

typedef unsigned short u16;
typedef short bf16x8 __attribute__((ext_vector_type(8)));
typedef unsigned short u16x8 __attribute__((ext_vector_type(8)));
typedef float f32x4 __attribute__((ext_vector_type(4)));

static __device__ __forceinline__ f32x4 mfma_bf16(bf16x8 a, bf16x8 b, f32x4 c) {
  return __builtin_amdgcn_mfma_f32_16x16x32_bf16(a, b, c, 0, 0, 0);
}

// fp32 -> bf16 RNE (bit-twiddle, prepass)
static __device__ __forceinline__ u16 f2b(float f) {
  unsigned int u = __float_as_uint(f);
  u = (u + 0x7FFFu + ((u >> 16) & 1u)) >> 16;
  return (u16)u;
}

// fp32 -> bf16 RNE via v_cvt_pk_bf16_f32 (1 VALU op; hot path)
static __device__ __forceinline__ u16 f2bq(float f) {
  unsigned int r;
  asm("v_cvt_pk_bf16_f32 %0, %1, %2" : "=v"(r) : "v"(f), "v"(f));
  return (u16)r;
}

// async global->LDS, 16B/lane. LDS dest = wave-uniform base + lane*16.
static __device__ __forceinline__ void gl16(const u16* g, u16* l) {
  __builtin_amdgcn_global_load_lds(
      (const __attribute__((address_space(1))) unsigned int*)(const void*)g,
      (__attribute__((address_space(3))) unsigned int*)(void*)l, 16, 0, 0);
}

// Fused fp32->bf16 for all 7 tensors (8 elems/thread, 16B stores) PLUS the
// RoPE cos/sin table (last 64 blocks) — one launch instead of two.
struct F2BArgs { const float* src[7]; u16* dst[7]; const float* fa; float* cs; };
__global__ __launch_bounds__(256) void k_f2bf_all(F2BArgs a) {
  int bid = blockIdx.x;
  if (bid >= 20480) {
    const int t0 = ((bid - 20480) * 256 + threadIdx.x) * 8;
    float4 a0 = *reinterpret_cast<const float4*>(a.fa + t0);
    float4 a1 = *reinterpret_cast<const float4*>(a.fa + t0 + 4);
    float4 o0, o1, o2, o3;
    o0.x = cosf(a0.x); o0.y = sinf(a0.x); o0.z = cosf(a0.y); o0.w = sinf(a0.y);
    o1.x = cosf(a0.z); o1.y = sinf(a0.z); o1.z = cosf(a0.w); o1.w = sinf(a0.w);
    o2.x = cosf(a1.x); o2.y = sinf(a1.x); o2.z = cosf(a1.y); o2.w = sinf(a1.y);
    o3.x = cosf(a1.z); o3.y = sinf(a1.z); o3.z = cosf(a1.w); o3.w = sinf(a1.w);
    float* out = a.cs + 2 * t0;
    *reinterpret_cast<float4*>(out)      = o0;
    *reinterpret_cast<float4*>(out + 4)  = o1;
    *reinterpret_cast<float4*>(out + 8)  = o2;
    *reinterpret_cast<float4*>(out + 12) = o3;
    return;
  }
  int buf, local;
  if (bid < 12288) { buf = bid >> 12; local = bid & 4095; }
  else { int t = bid - 12288; buf = 3 + (t >> 11); local = t & 2047; }
  const int i = (local * 256 + threadIdx.x) * 8;
  const float* in = a.src[buf];
  float4 v0 = *reinterpret_cast<const float4*>(in + i);
  float4 v1 = *reinterpret_cast<const float4*>(in + i + 4);
  u16x8 o;
  o[0]=f2b(v0.x); o[1]=f2b(v0.y); o[2]=f2b(v0.z); o[3]=f2b(v0.w);
  o[4]=f2b(v1.x); o[5]=f2b(v1.y); o[6]=f2b(v1.z); o[7]=f2b(v1.w);
  *reinterpret_cast<u16x8*>(a.dst[buf] + i) = o;
}

struct GemmJob { const u16* A; const u16* W; const float* bias; void* out; int mode; };
struct GemmArgs { GemmJob job[3]; };

// ============================================================================
// k_gemm3: 128x128 tile, BK=64, LDS double-buffer, issue-next-tile-first
// (round-7 best-measured structure, restored exactly).
// LDS 64 KiB -> 2 blocks/CU. mode: 0=bf16out,1=+RoPE,3=+RoPE+scale,2=fp32out.
// ============================================================================
__global__ __launch_bounds__(256, 2) void k_gemm3(GemmArgs ga, const float* __restrict__ cs) {
  const GemmJob J = ga.job[blockIdx.z];
  const u16* __restrict__ A = J.A;
  const u16* __restrict__ W = J.W;
  const int mode = J.mode;
  const int K = DD, N = DD;
  const int KT = K / 64;   // 32

  __shared__ __align__(16) u16 sA[2][128 * 64];   // 32 KiB
  __shared__ __align__(16) u16 sB[2][128 * 64];   // 32 KiB
  const int tid = threadIdx.x;
  const int l  = tid & 63;
  const int w  = tid >> 6;
  const int wr = w >> 1, wc = w & 1;
  const int bm = blockIdx.x * 128, bn = blockIdx.y * 128;
  const int lr = l & 15;
  const int lg = l >> 4;

  f32x4 acc[4][4];
#pragma unroll
  for (int mi = 0; mi < 4; mi++)
#pragma unroll
    for (int ni = 0; ni < 4; ni++)
#pragma unroll
      for (int j = 0; j < 4; j++) acc[mi][ni][j] = 0.0f;

  const int srcx = ((l & 7) * 8) ^ ((l >> 3) * 8);
  const u16* gAl = A + (size_t)(bm + w*32 + (l >> 3)) * K + srcx;
  const u16* gBl = W + (size_t)(bn + w*32 + (l >> 3)) * K + srcx;

  const int rx = (lr & 7) * 8;

  auto stage = [&](int kt) {
    u16* dA = &sA[kt & 1][(w * 32) * 64];
    u16* dB = &sB[kt & 1][(w * 32) * 64];
    const int k0 = kt * 64;
#pragma unroll
    for (int i = 0; i < 4; i++) gl16(gAl + (size_t)i*8*K + k0, dA + i * 512);
#pragma unroll
    for (int i = 0; i < 4; i++) gl16(gBl + (size_t)i*8*K + k0, dB + i * 512);
  };

  stage(0);
  __syncthreads();   // drains tile-0 loads

#pragma unroll 1
  for (int t = 0; t < KT; t++) {
    if (t + 1 < KT) stage(t + 1);          // issue FIRST: flies under compute
    const u16* a_ = sA[t & 1];
    const u16* b_ = sB[t & 1];
#pragma unroll
    for (int kk = 0; kk < 2; kk++) {
      bf16x8 af[4], bfv[4];
#pragma unroll
      for (int i = 0; i < 4; i++)
        af[i]  = *reinterpret_cast<const bf16x8*>(
            a_ + (wr*64 + i*16 + lr) * 64 + ((kk*32 + lg*8) ^ rx));
#pragma unroll
      for (int i = 0; i < 4; i++)
        bfv[i] = *reinterpret_cast<const bf16x8*>(
            b_ + (wc*64 + i*16 + lr) * 64 + ((kk*32 + lg*8) ^ rx));
#pragma unroll
      for (int mi = 0; mi < 4; mi++)
#pragma unroll
        for (int ni = 0; ni < 4; ni++)
          acc[mi][ni] = mfma_bf16(af[mi], bfv[ni], acc[mi][ni]);
    }
    __syncthreads();   // drains t+1 loads (issued ~compute ago) + LDS hazards
  }

  // Epilogue. D-layout: col = lane&15, row = (lane>>4)*4 + reg.
#pragma unroll
  for (int mi = 0; mi < 4; mi++) {
#pragma unroll
    for (int ni = 0; ni < 4; ni++) {
      const int col = bn + wc*64 + ni*16 + lr;
      const float bv = J.bias[col];
#pragma unroll
      for (int r = 0; r < 4; r++) {
        const int row = bm + wr*64 + mi*16 + lg*4 + r;
        float v = acc[mi][ni][r] + bv;
        if (mode & 1) {
          const int s  = row & (SS - 1);
          const int dk = col & (DKK - 1);
          const int p  = dk >> 1;
          const float2 csv = *reinterpret_cast<const float2*>(cs + (size_t)(s*64 + p)*2);
          const float other = __shfl_xor(v, 1);
          const float sgn = (dk & 1) ? csv.y : -csv.y;
          v = v * csv.x + other * sgn;
          if (mode == 3) v *= 0.12751744f;   // (1/sqrt(128)) * log2(e)
        }
        if (mode == 2) {
          reinterpret_cast<float*>(J.out)[(size_t)row * N + col] = v;
        } else {
          reinterpret_cast<u16*>(J.out)[(size_t)row * N + col] = f2b(v);
        }
      }
    }
  }
}

// ============================================================================
// Flash attention, causal, exp2 domain. 64-ROW q-tiles -> 1024 blocks:
// 512 resident (2/CU) + 512 BACKFILL, heavy-first (j = 31 - bid>>5) ->
// greedy makespan ~ total/512 instead of the 32-tile straggler (the 512-block
// version had blocks == slots -> zero backfill, ~45% tail waste).
// 4 waves x 16 q-rows; KVBLK=64; kv = 0..j, diagonal mask only at kv == j.
// LDS 57 KB (K dbuf 32 + VT 16 + PL 9) -> 2 blocks/CU.
// ============================================================================
__global__ __launch_bounds__(256, 2) void k_attn(const u16* __restrict__ Qp,
                                                 const u16* __restrict__ Kp,
                                                 const u16* __restrict__ Vp,
                                                 u16* __restrict__ Op) {
  const int bid = blockIdx.x;
  const int j  = 31 - (bid >> 5);     // q-tile index (64 rows), heavy first
  const int bh = bid & 31;
  const int h  = bh & 15;
  const int b  = bh >> 4;
  const int tid = threadIdx.x;
  const int l  = tid & 63, w = tid >> 6;
  const int lr = l & 15, lg = l >> 4;
  const int q0 = j * 64;              // first q-row of this block

  __shared__ __align__(16) u16 Klds[2 * 64 * 128];  // 32 KB (dbuf)
  __shared__ __align__(16) u16 VT[128 * 64];        // 16 KB
  __shared__ __align__(16) u16 PL[4][16][72];       // 9 KB

  // K staging: wave w stages rows [w*16, w*16+16), 4 gl16 of 4 rows each.
  int koff[4];
#pragma unroll
  for (int i = 0; i < 4; i++) {
    const int row = w*16 + i*4 + (l >> 4);
    koff[i] = row * DD + (((l & 15) * 8) ^ ((row & 7) * 8));
  }
  const u16* kbase = Kp + (size_t)b * SS * DD + h * DKK;

  // V staging: thread -> keys k0v..k0v+7 (8 rows) x d-range d0..d0+3 (uint2).
  const int k0v = (tid >> 5) * 8;   // 0,8,...,56
  const int d0  = (tid & 31) * 4;   // 0,4,...,124
  const u16* vbase = Vp + (size_t)b * SS * DD + h * DKK + (size_t)k0v * DD + d0;

  uint2 vr[8];

  auto stageK = [&](int nk, int bufq) {
    const u16* kb = kbase + (size_t)nk * (64 * DD);
    u16* dst = Klds + bufq * 8192 + (w * 16) * 128;
#pragma unroll
    for (int i = 0; i < 4; i++) gl16(kb + koff[i], dst + i * 512);
  };
  auto prefV = [&](int nk) {
    const u16* vb = vbase + (size_t)nk * (64 * DD);
#pragma unroll
    for (int c = 0; c < 8; c++) vr[c] = *reinterpret_cast<const uint2*>(vb + c * DD);
  };

  int cur = 0;
  stageK(0, 0);
  prefV(0);

  // Hoist Q fragments: 16 rows/wave x 4 k-slices
  bf16x8 qf[4];
  {
    const size_t qrow = (size_t)(b*SS + q0 + w*16 + lr) * DD + h*DKK;
#pragma unroll
    for (int kk = 0; kk < 4; kk++)
      qf[kk] = *reinterpret_cast<const bf16x8*>(Qp + qrow + kk*32 + lg*8);
  }

  float m[4], lsum[4];
  f32x4 oacc[8];
#pragma unroll
  for (int r = 0; r < 4; r++) { m[r] = -INFINITY; lsum[r] = 0.0f; }
#pragma unroll
  for (int dt = 0; dt < 8; dt++)
#pragma unroll
    for (int jj = 0; jj < 4; jj++) oacc[dt][jj] = 0.0f;

#pragma unroll 1
  for (int kv = 0; kv <= j; kv++) {
    __syncthreads();   // prev iter LDS reads done; K[cur] gl16 + vr loads drained
    // write prefetched V -> swizzled VT: VT[row=d][col=key ^ g(row)]
#pragma unroll
    for (int dj = 0; dj < 4; dj++) {
      const int row = d0 + dj;
      const int col = k0v ^ (((row ^ (row >> 3)) & 7) * 8);
      u16x8 pk;
#pragma unroll
      for (int jq = 0; jq < 8; jq++) pk[jq] = reinterpret_cast<const u16*>(&vr[jq])[dj];
      *reinterpret_cast<u16x8*>(VT + row * 64 + col) = pk;
    }
    __syncthreads();   // VT ready; K[cur] visible to all waves

    const bool hasnext = (kv < j);
    if (hasnext) {
      prefV(kv + 1);               // global->reg, hides under compute
      stageK(kv + 1, cur ^ 1);     // gl16, drained at next top barrier
    }

    // ---- S = Q K^T (16 q-rows x 64 keys per wave) ----
    f32x4 sa[4];
#pragma unroll
    for (int kt = 0; kt < 4; kt++)
#pragma unroll
      for (int jj = 0; jj < 4; jj++) sa[kt][jj] = 0.0f;
    const u16* kl = Klds + cur * 8192;
    __builtin_amdgcn_s_setprio(1);
#pragma unroll
    for (int kk = 0; kk < 4; kk++) {
#pragma unroll
      for (int kt = 0; kt < 4; kt++) {
        const int row = kt*16 + lr;
        const bf16x8 kf = *reinterpret_cast<const bf16x8*>(
            kl + row * 128 + ((kk*32 + lg*8) ^ ((row & 7) * 8)));
        sa[kt] = mfma_bf16(qf[kk], kf, sa[kt]);
      }
    }
    __builtin_amdgcn_s_setprio(0);

    // causal mask: only the diagonal tile (kv == j) straddles
    if (kv == j) {
#pragma unroll
      for (int kt = 0; kt < 4; kt++) {
        const int key = kt*16 + lr;                  // within tile
#pragma unroll
        for (int r = 0; r < 4; r++) {
          const int qv = w*16 + lg*4 + r;            // within tile
          if (key > qv) sa[kt][r] = -1e9f;
        }
      }
    }

    // defer-max (THR=8): lane-local check, rescale rarely
    float pm[4];
#pragma unroll
    for (int r = 0; r < 4; r++)
      pm[r] = fmaxf(fmaxf(sa[0][r], sa[1][r]), fmaxf(sa[2][r], sa[3][r]));
    bool ok = true;
#pragma unroll
    for (int r = 0; r < 4; r++) ok = ok && (pm[r] <= m[r] + 8.0f);
    if (!__all(ok)) {
#pragma unroll
      for (int r = 0; r < 4; r++) {
        float t = pm[r];
#pragma unroll
        for (int d = 1; d < 16; d <<= 1) t = fmaxf(t, __shfl_xor(t, d));
        const float mnew = fmaxf(m[r], t);
        const float corr = exp2f(m[r] - mnew);
        lsum[r] *= corr;
#pragma unroll
        for (int dt = 0; dt < 8; dt++) oacc[dt][r] *= corr;
        m[r] = mnew;
      }
    }

    // exp2 + lane-partial sums + P -> per-wave LDS
#pragma unroll
    for (int r = 0; r < 4; r++) {
      float rs = 0.0f;
#pragma unroll
      for (int kt = 0; kt < 4; kt++) {
        const float e = exp2f(sa[kt][r] - m[r]);
        rs += e;
        PL[w][lg*4 + r][kt*16 + lr] = f2bq(e);
      }
      lsum[r] += rs;
    }

    // ---- O += P V ----
    __builtin_amdgcn_s_setprio(1);
#pragma unroll
    for (int kk2 = 0; kk2 < 2; kk2++) {
      const bf16x8 pa = *reinterpret_cast<const bf16x8*>(&PL[w][lr][kk2*32 + lg*8]);
#pragma unroll
      for (int dt = 0; dt < 8; dt++) {
        const int row = dt*16 + lr;
        const bf16x8 vb = *reinterpret_cast<const bf16x8*>(
            VT + row * 64 + ((kk2*32 + lg*8) ^ (((row ^ (row >> 3)) & 7) * 8)));
        oacc[dt] = mfma_bf16(pa, vb, oacc[dt]);
      }
    }
    __builtin_amdgcn_s_setprio(0);

    if (hasnext) cur ^= 1;
  }

  // epilogue: reduce lane-partial lsum across 16 lanes, normalize, store
  float inv[4];
#pragma unroll
  for (int r = 0; r < 4; r++) {
    float t = lsum[r];
#pragma unroll
    for (int d = 1; d < 16; d <<= 1) t += __shfl_xor(t, d);
    inv[r] = 1.0f / t;
  }
#pragma unroll
  for (int dt = 0; dt < 8; dt++)
#pragma unroll
    for (int r = 0; r < 4; r++) {
      const size_t row = (size_t)(b*SS + q0 + w*16 + lg*4 + r);
      Op[row * DD + h*DKK + dt*16 + lr] = f2bq(oacc[dt][r] * inv[r]);
    }
}

extern "C" void kernel_launch(void* const* d_in, const int* in_sizes, int n_in,
                              void* d_out, int out_size, void* d_ws, size_t ws_size,
                              hipStream_t stream) {
  const float* q  = (const float*)d_in[0];
  const float* k  = (const float*)d_in[1];
  const float* v  = (const float*)d_in[2];
  const float* fa = (const float*)d_in[4];
  const float* wq = (const float*)d_in[5];
  const float* bq = (const float*)d_in[6];
  const float* wk = (const float*)d_in[7];
  const float* bk = (const float*)d_in[8];
  const float* wv = (const float*)d_in[9];
  const float* bv = (const float*)d_in[10];
  const float* wo = (const float*)d_in[11];
  const float* bo = (const float*)d_in[12];

  float* cs = (float*)d_ws;
  u16* bf = (u16*)((char*)d_ws + (size_t)262144 * sizeof(float));
  const size_t NX = (size_t)MM * DD;
  const size_t NW = (size_t)DD * DD;
  u16* q_bf  = bf;
  u16* k_bf  = q_bf + NX;
  u16* v_bf  = k_bf + NX;
  u16* wq_bf = v_bf + NX;
  u16* wk_bf = wq_bf + NW;
  u16* wv_bf = wk_bf + NW;
  u16* wo_bf = wv_bf + NW;
  u16* Qp    = wo_bf + NW;
  u16* Kp    = Qp + NX;
  u16* Vp    = Kp + NX;
  u16* Ao    = Vp + NX;

  F2BArgs fa7;
  fa7.src[0] = q;  fa7.dst[0] = q_bf;
  fa7.src[1] = k;  fa7.dst[1] = k_bf;
  fa7.src[2] = v;  fa7.dst[2] = v_bf;
  fa7.src[3] = wq; fa7.dst[3] = wq_bf;
  fa7.src[4] = wk; fa7.dst[4] = wk_bf;
  fa7.src[5] = wv; fa7.dst[5] = wv_bf;
  fa7.src[6] = wo; fa7.dst[6] = wo_bf;
  fa7.fa = fa;     fa7.cs = cs;
  // 20480 conversion blocks + 64 cos/sin-table blocks
  k_f2bf_all<<<dim3(20544), 256, 0, stream>>>(fa7);

  // fused QKV projections: dbuf 128^2 kernel, grid 32x16x3 = 1536 blocks
  GemmArgs gq;
  gq.job[0] = GemmJob{ q_bf, wq_bf, bq, (void*)Qp, 3 };
  gq.job[1] = GemmJob{ k_bf, wk_bf, bk, (void*)Kp, 1 };
  gq.job[2] = GemmJob{ v_bf, wv_bf, bv, (void*)Vp, 0 };
  k_gemm3<<<dim3(MM/128, DD/128, 3), 256, 0, stream>>>(gq, cs);

  // attention: 1024 blocks of 64 q-rows, heavy-first -> greedy backfill
  k_attn<<<dim3(1024), 256, 0, stream>>>(Qp, Kp, Vp, Ao);

  // output projection: 512 blocks = exactly 2 blocks/CU, one round
  GemmArgs go;
  go.job[0] = GemmJob{ Ao, wo_bf, bo, d_out, 2 };
  go.job[1] = go.job[0];
  go.job[2] = go.job[0];
  k_gemm3<<<dim3(MM/128, DD/128, 1), 256, 0, stream>>>(go, cs);
}

// Round 11
// 298.944 us; speedup vs baseline: 1.2575x; 1.0178x over previous
//
#include <hip/hip_runtime.h>
#include <hip/hip_bf16.h>

// Problem constants
#define BB 2
#define SS 2048
#define DD 2048
#define HH 16
#define DKK 128
#define MM (BB*SS)   // 4096 token rows

typedef unsigned short u16;
typedef short bf16x8 __attribute__((ext_vector_type(8)));
typedef unsigned short u16x8 __attribute__((ext_vector_type(8)));
typedef float f32x4 __attribute__((ext_vector_type(4)));

static __device__ __forceinline__ f32x4 mfma_bf16(bf16x8 a, bf16x8 b, f32x4 c) {
  return __builtin_amdgcn_mfma_f32_16x16x32_bf16(a, b, c, 0, 0, 0);
}

// fp32 -> bf16 RNE (bit-twiddle, prepass)
static __device__ __forceinline__ u16 f2b(float f) {
  unsigned int u = __float_as_uint(f);
  u = (u + 0x7FFFu + ((u >> 16) & 1u)) >> 16;
  return (u16)u;
}

// fp32 -> bf16 RNE via v_cvt_pk_bf16_f32 (1 VALU op; hot path)
static __device__ __forceinline__ u16 f2bq(float f) {
  unsigned int r;
  asm("v_cvt_pk_bf16_f32 %0, %1, %2" : "=v"(r) : "v"(f), "v"(f));
  return (u16)r;
}

// async global->LDS, 16B/lane. LDS dest = wave-uniform base + lane*16.
static __device__ __forceinline__ void gl16(const u16* g, u16* l) {
  __builtin_amdgcn_global_load_lds(
      (const __attribute__((address_space(1))) unsigned int*)(const void*)g,
      (__attribute__((address_space(3))) unsigned int*)(void*)l, 16, 0, 0);
}

// Fused fp32->bf16 for all 7 tensors (8 elems/thread, 16B stores) PLUS the
// RoPE cos/sin table (last 64 blocks) — one launch instead of two.
struct F2BArgs { const float* src[7]; u16* dst[7]; const float* fa; float* cs; };
__global__ __launch_bounds__(256) void k_f2bf_all(F2BArgs a) {
  int bid = blockIdx.x;
  if (bid >= 20480) {
    const int t0 = ((bid - 20480) * 256 + threadIdx.x) * 8;
    float4 a0 = *reinterpret_cast<const float4*>(a.fa + t0);
    float4 a1 = *reinterpret_cast<const float4*>(a.fa + t0 + 4);
    float4 o0, o1, o2, o3;
    o0.x = cosf(a0.x); o0.y = sinf(a0.x); o0.z = cosf(a0.y); o0.w = sinf(a0.y);
    o1.x = cosf(a0.z); o1.y = sinf(a0.z); o1.z = cosf(a0.w); o1.w = sinf(a0.w);
    o2.x = cosf(a1.x); o2.y = sinf(a1.x); o2.z = cosf(a1.y); o2.w = sinf(a1.y);
    o3.x = cosf(a1.z); o3.y = sinf(a1.z); o3.z = cosf(a1.w); o3.w = sinf(a1.w);
    float* out = a.cs + 2 * t0;
    *reinterpret_cast<float4*>(out)      = o0;
    *reinterpret_cast<float4*>(out + 4)  = o1;
    *reinterpret_cast<float4*>(out + 8)  = o2;
    *reinterpret_cast<float4*>(out + 12) = o3;
    return;
  }
  int buf, local;
  if (bid < 12288) { buf = bid >> 12; local = bid & 4095; }
  else { int t = bid - 12288; buf = 3 + (t >> 11); local = t & 2047; }
  const int i = (local * 256 + threadIdx.x) * 8;
  const float* in = a.src[buf];
  float4 v0 = *reinterpret_cast<const float4*>(in + i);
  float4 v1 = *reinterpret_cast<const float4*>(in + i + 4);
  u16x8 o;
  o[0]=f2b(v0.x); o[1]=f2b(v0.y); o[2]=f2b(v0.z); o[3]=f2b(v0.w);
  o[4]=f2b(v1.x); o[5]=f2b(v1.y); o[6]=f2b(v1.z); o[7]=f2b(v1.w);
  *reinterpret_cast<u16x8*>(a.dst[buf] + i) = o;
}

struct GemmJob { const u16* A; const u16* W; const float* bias; void* out; int mode; };
struct GemmArgs { GemmJob job[3]; };

// ============================================================================
// k_gemm3: 128x128 tile, BK=64, LDS double-buffer, issue-next-tile-first
// (round-7 best-measured structure, frozen).
// LDS 64 KiB -> 2 blocks/CU. mode: 0=bf16out,1=+RoPE,3=+RoPE+scale,2=fp32out.
// ============================================================================
__global__ __launch_bounds__(256, 2) void k_gemm3(GemmArgs ga, const float* __restrict__ cs) {
  const GemmJob J = ga.job[blockIdx.z];
  const u16* __restrict__ A = J.A;
  const u16* __restrict__ W = J.W;
  const int mode = J.mode;
  const int K = DD, N = DD;
  const int KT = K / 64;   // 32

  __shared__ __align__(16) u16 sA[2][128 * 64];   // 32 KiB
  __shared__ __align__(16) u16 sB[2][128 * 64];   // 32 KiB
  const int tid = threadIdx.x;
  const int l  = tid & 63;
  const int w  = tid >> 6;
  const int wr = w >> 1, wc = w & 1;
  const int bm = blockIdx.x * 128, bn = blockIdx.y * 128;
  const int lr = l & 15;
  const int lg = l >> 4;

  f32x4 acc[4][4];
#pragma unroll
  for (int mi = 0; mi < 4; mi++)
#pragma unroll
    for (int ni = 0; ni < 4; ni++)
#pragma unroll
      for (int j = 0; j < 4; j++) acc[mi][ni][j] = 0.0f;

  const int srcx = ((l & 7) * 8) ^ ((l >> 3) * 8);
  const u16* gAl = A + (size_t)(bm + w*32 + (l >> 3)) * K + srcx;
  const u16* gBl = W + (size_t)(bn + w*32 + (l >> 3)) * K + srcx;

  const int rx = (lr & 7) * 8;

  auto stage = [&](int kt) {
    u16* dA = &sA[kt & 1][(w * 32) * 64];
    u16* dB = &sB[kt & 1][(w * 32) * 64];
    const int k0 = kt * 64;
#pragma unroll
    for (int i = 0; i < 4; i++) gl16(gAl + (size_t)i*8*K + k0, dA + i * 512);
#pragma unroll
    for (int i = 0; i < 4; i++) gl16(gBl + (size_t)i*8*K + k0, dB + i * 512);
  };

  stage(0);
  __syncthreads();   // drains tile-0 loads

#pragma unroll 1
  for (int t = 0; t < KT; t++) {
    if (t + 1 < KT) stage(t + 1);          // issue FIRST: flies under compute
    const u16* a_ = sA[t & 1];
    const u16* b_ = sB[t & 1];
#pragma unroll
    for (int kk = 0; kk < 2; kk++) {
      bf16x8 af[4], bfv[4];
#pragma unroll
      for (int i = 0; i < 4; i++)
        af[i]  = *reinterpret_cast<const bf16x8*>(
            a_ + (wr*64 + i*16 + lr) * 64 + ((kk*32 + lg*8) ^ rx));
#pragma unroll
      for (int i = 0; i < 4; i++)
        bfv[i] = *reinterpret_cast<const bf16x8*>(
            b_ + (wc*64 + i*16 + lr) * 64 + ((kk*32 + lg*8) ^ rx));
#pragma unroll
      for (int mi = 0; mi < 4; mi++)
#pragma unroll
        for (int ni = 0; ni < 4; ni++)
          acc[mi][ni] = mfma_bf16(af[mi], bfv[ni], acc[mi][ni]);
    }
    __syncthreads();   // drains t+1 loads (issued ~compute ago) + LDS hazards
  }

  // Epilogue. D-layout: col = lane&15, row = (lane>>4)*4 + reg.
#pragma unroll
  for (int mi = 0; mi < 4; mi++) {
#pragma unroll
    for (int ni = 0; ni < 4; ni++) {
      const int col = bn + wc*64 + ni*16 + lr;
      const float bv = J.bias[col];
#pragma unroll
      for (int r = 0; r < 4; r++) {
        const int row = bm + wr*64 + mi*16 + lg*4 + r;
        float v = acc[mi][ni][r] + bv;
        if (mode & 1) {
          const int s  = row & (SS - 1);
          const int dk = col & (DKK - 1);
          const int p  = dk >> 1;
          const float2 csv = *reinterpret_cast<const float2*>(cs + (size_t)(s*64 + p)*2);
          const float other = __shfl_xor(v, 1);
          const float sgn = (dk & 1) ? csv.y : -csv.y;
          v = v * csv.x + other * sgn;
          if (mode == 3) v *= 0.12751744f;   // (1/sqrt(128)) * log2(e)
        }
        if (mode == 2) {
          reinterpret_cast<float*>(J.out)[(size_t)row * N + col] = v;
        } else {
          reinterpret_cast<u16*>(J.out)[(size_t)row * N + col] = f2b(v);
        }
      }
    }
  }
}

// ============================================================================
// Flash attention, causal, exp2 domain. 64-row q-tiles, KVBLK=64, PAIRED:
// block (p, bh) processes tiles j_hi = 31-p then j_lo = p sequentially ->
// cost = (32-p) + (p+1) = 33 kv-units for EVERY block. 512 blocks, all
// resident (2/CU), zero tail by construction (r10's heavy-first LPT still
// had ~15% straggler waste). __syncthreads() between halves guards the
// Klds/VT overwrite vs half-0's final reads.
// 4 waves x 16 q-rows; kv = 0..j, diagonal mask only at kv == j.
// LDS 57 KB (K dbuf 32 + VT 16 + PL 9) -> 2 blocks/CU.
// ============================================================================
__global__ __launch_bounds__(256, 2) void k_attn(const u16* __restrict__ Qp,
                                                 const u16* __restrict__ Kp,
                                                 const u16* __restrict__ Vp,
                                                 u16* __restrict__ Op) {
  const int bid = blockIdx.x;
  const int p  = bid >> 5;            // 0..15 (pair index)
  const int bh = bid & 31;
  const int h  = bh & 15;
  const int b  = bh >> 4;
  const int tid = threadIdx.x;
  const int l  = tid & 63, w = tid >> 6;
  const int lr = l & 15, lg = l >> 4;

  __shared__ __align__(16) u16 Klds[2 * 64 * 128];  // 32 KB (dbuf)
  __shared__ __align__(16) u16 VT[128 * 64];        // 16 KB
  __shared__ __align__(16) u16 PL[4][16][72];       // 9 KB

  // K staging: wave w stages rows [w*16, w*16+16), 4 gl16 of 4 rows each.
  int koff[4];
#pragma unroll
  for (int i = 0; i < 4; i++) {
    const int row = w*16 + i*4 + (l >> 4);
    koff[i] = row * DD + (((l & 15) * 8) ^ ((row & 7) * 8));
  }
  const u16* kbase = Kp + (size_t)b * SS * DD + h * DKK;

  // V staging: thread -> keys k0v..k0v+7 (8 rows) x d-range d0..d0+3 (uint2).
  const int k0v = (tid >> 5) * 8;   // 0,8,...,56
  const int d0  = (tid & 31) * 4;   // 0,4,...,124
  const u16* vbase = Vp + (size_t)b * SS * DD + h * DKK + (size_t)k0v * DD + d0;

  uint2 vr[8];

  auto stageK = [&](int nk, int bufq) {
    const u16* kb = kbase + (size_t)nk * (64 * DD);
    u16* dst = Klds + bufq * 8192 + (w * 16) * 128;
#pragma unroll
    for (int i = 0; i < 4; i++) gl16(kb + koff[i], dst + i * 512);
  };
  auto prefV = [&](int nk) {
    const u16* vb = vbase + (size_t)nk * (64 * DD);
#pragma unroll
    for (int c = 0; c < 8; c++) vr[c] = *reinterpret_cast<const uint2*>(vb + c * DD);
  };

#pragma unroll 1
  for (int half = 0; half < 2; half++) {
    const int j  = half ? p : (31 - p);   // tile pair: 31-p then p
    const int q0 = j * 64;

    if (half) __syncthreads();   // half-0's final Klds/VT reads done before restage

    int cur = 0;
    stageK(0, 0);
    prefV(0);

    // Hoist Q fragments: 16 rows/wave x 4 k-slices
    bf16x8 qf[4];
    {
      const size_t qrow = (size_t)(b*SS + q0 + w*16 + lr) * DD + h*DKK;
#pragma unroll
      for (int kk = 0; kk < 4; kk++)
        qf[kk] = *reinterpret_cast<const bf16x8*>(Qp + qrow + kk*32 + lg*8);
    }

    float m[4], lsum[4];
    f32x4 oacc[8];
#pragma unroll
    for (int r = 0; r < 4; r++) { m[r] = -INFINITY; lsum[r] = 0.0f; }
#pragma unroll
    for (int dt = 0; dt < 8; dt++)
#pragma unroll
      for (int jj = 0; jj < 4; jj++) oacc[dt][jj] = 0.0f;

#pragma unroll 1
    for (int kv = 0; kv <= j; kv++) {
      __syncthreads();   // prev iter LDS reads done; K[cur] gl16 + vr loads drained
      // write prefetched V -> swizzled VT: VT[row=d][col=key ^ g(row)]
#pragma unroll
      for (int dj = 0; dj < 4; dj++) {
        const int row = d0 + dj;
        const int col = k0v ^ (((row ^ (row >> 3)) & 7) * 8);
        u16x8 pk;
#pragma unroll
        for (int jq = 0; jq < 8; jq++) pk[jq] = reinterpret_cast<const u16*>(&vr[jq])[dj];
        *reinterpret_cast<u16x8*>(VT + row * 64 + col) = pk;
      }
      __syncthreads();   // VT ready; K[cur] visible to all waves

      const bool hasnext = (kv < j);
      if (hasnext) {
        prefV(kv + 1);               // global->reg, hides under compute
        stageK(kv + 1, cur ^ 1);     // gl16, drained at next top barrier
      }

      // ---- S = Q K^T (16 q-rows x 64 keys per wave) ----
      f32x4 sa[4];
#pragma unroll
      for (int kt = 0; kt < 4; kt++)
#pragma unroll
        for (int jj = 0; jj < 4; jj++) sa[kt][jj] = 0.0f;
      const u16* kl = Klds + cur * 8192;
      __builtin_amdgcn_s_setprio(1);
#pragma unroll
      for (int kk = 0; kk < 4; kk++) {
#pragma unroll
        for (int kt = 0; kt < 4; kt++) {
          const int row = kt*16 + lr;
          const bf16x8 kf = *reinterpret_cast<const bf16x8*>(
              kl + row * 128 + ((kk*32 + lg*8) ^ ((row & 7) * 8)));
          sa[kt] = mfma_bf16(qf[kk], kf, sa[kt]);
        }
      }
      __builtin_amdgcn_s_setprio(0);

      // causal mask: only the diagonal tile (kv == j) straddles
      if (kv == j) {
#pragma unroll
        for (int kt = 0; kt < 4; kt++) {
          const int key = kt*16 + lr;                  // within tile
#pragma unroll
          for (int r = 0; r < 4; r++) {
            const int qv = w*16 + lg*4 + r;            // within tile
            if (key > qv) sa[kt][r] = -1e9f;
          }
        }
      }

      // defer-max (THR=8): lane-local check, rescale rarely
      float pm[4];
#pragma unroll
      for (int r = 0; r < 4; r++)
        pm[r] = fmaxf(fmaxf(sa[0][r], sa[1][r]), fmaxf(sa[2][r], sa[3][r]));
      bool ok = true;
#pragma unroll
      for (int r = 0; r < 4; r++) ok = ok && (pm[r] <= m[r] + 8.0f);
      if (!__all(ok)) {
#pragma unroll
        for (int r = 0; r < 4; r++) {
          float t = pm[r];
#pragma unroll
          for (int d = 1; d < 16; d <<= 1) t = fmaxf(t, __shfl_xor(t, d));
          const float mnew = fmaxf(m[r], t);
          const float corr = exp2f(m[r] - mnew);
          lsum[r] *= corr;
#pragma unroll
          for (int dt = 0; dt < 8; dt++) oacc[dt][r] *= corr;
          m[r] = mnew;
        }
      }

      // exp2 + lane-partial sums + P -> per-wave LDS
#pragma unroll
      for (int r = 0; r < 4; r++) {
        float rs = 0.0f;
#pragma unroll
        for (int kt = 0; kt < 4; kt++) {
          const float e = exp2f(sa[kt][r] - m[r]);
          rs += e;
          PL[w][lg*4 + r][kt*16 + lr] = f2bq(e);
        }
        lsum[r] += rs;
      }

      // ---- O += P V ----
      __builtin_amdgcn_s_setprio(1);
#pragma unroll
      for (int kk2 = 0; kk2 < 2; kk2++) {
        const bf16x8 pa = *reinterpret_cast<const bf16x8*>(&PL[w][lr][kk2*32 + lg*8]);
#pragma unroll
        for (int dt = 0; dt < 8; dt++) {
          const int row = dt*16 + lr;
          const bf16x8 vb = *reinterpret_cast<const bf16x8*>(
              VT + row * 64 + ((kk2*32 + lg*8) ^ (((row ^ (row >> 3)) & 7) * 8)));
          oacc[dt] = mfma_bf16(pa, vb, oacc[dt]);
        }
      }
      __builtin_amdgcn_s_setprio(0);

      if (hasnext) cur ^= 1;
    }

    // epilogue: reduce lane-partial lsum across 16 lanes, normalize, store
    float inv[4];
#pragma unroll
    for (int r = 0; r < 4; r++) {
      float t = lsum[r];
#pragma unroll
      for (int d = 1; d < 16; d <<= 1) t += __shfl_xor(t, d);
      inv[r] = 1.0f / t;
    }
#pragma unroll
    for (int dt = 0; dt < 8; dt++)
#pragma unroll
      for (int r = 0; r < 4; r++) {
        const size_t row = (size_t)(b*SS + q0 + w*16 + lg*4 + r);
        Op[row * DD + h*DKK + dt*16 + lr] = f2bq(oacc[dt][r] * inv[r]);
      }
  }
}

extern "C" void kernel_launch(void* const* d_in, const int* in_sizes, int n_in,
                              void* d_out, int out_size, void* d_ws, size_t ws_size,
                              hipStream_t stream) {
  const float* q  = (const float*)d_in[0];
  const float* k  = (const float*)d_in[1];
  const float* v  = (const float*)d_in[2];
  const float* fa = (const float*)d_in[4];
  const float* wq = (const float*)d_in[5];
  const float* bq = (const float*)d_in[6];
  const float* wk = (const float*)d_in[7];
  const float* bk = (const float*)d_in[8];
  const float* wv = (const float*)d_in[9];
  const float* bv = (const float*)d_in[10];
  const float* wo = (const float*)d_in[11];
  const float* bo = (const float*)d_in[12];

  float* cs = (float*)d_ws;
  u16* bf = (u16*)((char*)d_ws + (size_t)262144 * sizeof(float));
  const size_t NX = (size_t)MM * DD;
  const size_t NW = (size_t)DD * DD;
  u16* q_bf  = bf;
  u16* k_bf  = q_bf + NX;
  u16* v_bf  = k_bf + NX;
  u16* wq_bf = v_bf + NX;
  u16* wk_bf = wq_bf + NW;
  u16* wv_bf = wk_bf + NW;
  u16* wo_bf = wv_bf + NW;
  u16* Qp    = wo_bf + NW;
  u16* Kp    = Qp + NX;
  u16* Vp    = Kp + NX;
  u16* Ao    = Vp + NX;

  F2BArgs fa7;
  fa7.src[0] = q;  fa7.dst[0] = q_bf;
  fa7.src[1] = k;  fa7.dst[1] = k_bf;
  fa7.src[2] = v;  fa7.dst[2] = v_bf;
  fa7.src[3] = wq; fa7.dst[3] = wq_bf;
  fa7.src[4] = wk; fa7.dst[4] = wk_bf;
  fa7.src[5] = wv; fa7.dst[5] = wv_bf;
  fa7.src[6] = wo; fa7.dst[6] = wo_bf;
  fa7.fa = fa;     fa7.cs = cs;
  // 20480 conversion blocks + 64 cos/sin-table blocks
  k_f2bf_all<<<dim3(20544), 256, 0, stream>>>(fa7);

  // fused QKV projections: dbuf 128^2 kernel, grid 32x16x3 = 1536 blocks
  GemmArgs gq;
  gq.job[0] = GemmJob{ q_bf, wq_bf, bq, (void*)Qp, 3 };
  gq.job[1] = GemmJob{ k_bf, wk_bf, bk, (void*)Kp, 1 };
  gq.job[2] = GemmJob{ v_bf, wv_bf, bv, (void*)Vp, 0 };
  k_gemm3<<<dim3(MM/128, DD/128, 3), 256, 0, stream>>>(gq, cs);

  // attention: 512 paired blocks (cost-33 uniform), all resident, no tail
  k_attn<<<dim3(512), 256, 0, stream>>>(Qp, Kp, Vp, Ao);

  // output projection: 512 blocks = exactly 2 blocks/CU, one round
  GemmArgs go;
  go.job[0] = GemmJob{ Ao, wo_bf, bo, d_out, 2 };
  go.job[1] = go.job[0];
  go.job[2] = go.job[0];
  k_gemm3<<<dim3(MM/128, DD/128, 1), 256, 0, stream>>>(go, cs);
}